// Round 3
// baseline (385.068 us; speedup 1.0000x reference)
//
#include <hip/hip_runtime.h>
#include <hip/hip_bf16.h>

typedef short bf16x8 __attribute__((ext_vector_type(8)));
typedef float f32x4 __attribute__((ext_vector_type(4)));
typedef float f32x16 __attribute__((ext_vector_type(16)));
typedef __hip_bfloat16 bf16;
typedef unsigned int uint;

static constexpr int Bn = 4, Nn = 2048, Cn = 1024, Hn = 16, Dn = 64;
static constexpr float kEps = 1e-6f;

// ---------------- f32 -> bf16 convert (4 elems/thread) ----------------
__global__ __launch_bounds__(256) void cvt_kernel(const float* __restrict__ in,
                                                  bf16* __restrict__ out, int n4) {
  int i = blockIdx.x * 256 + threadIdx.x;
  if (i >= n4) return;
  const float4 v = reinterpret_cast<const float4*>(in)[i];
  bf16 t[4];
  t[0] = __float2bfloat16(v.x); t[1] = __float2bfloat16(v.y);
  t[2] = __float2bfloat16(v.z); t[3] = __float2bfloat16(v.w);
  reinterpret_cast<uint2*>(out)[i] = *reinterpret_cast<const uint2*>(t);
}

// ---------------- bf16 GEMM, C = A(MxK) * B(NxK)^T ----------------
template <int EPI>
__global__ __launch_bounds__(256) void gemm_bt(
    const bf16* __restrict__ A, const bf16* __restrict__ Bw,
    float* __restrict__ Cf, bf16* __restrict__ q_raw, bf16* __restrict__ k_raw,
    bf16* __restrict__ v_buf, int N, int K) {
  __shared__ bf16 As[128 * 40];
  __shared__ bf16 Bs[128 * 40];
  const int tid = threadIdx.x;
  const int lane = tid & 63, w = tid >> 6;
  const int wr = w >> 1, wc = w & 1;
  const int l15 = lane & 15, l4 = lane >> 4;
  const int m0 = blockIdx.y * 128, n0 = blockIdx.x * 128;
  f32x4 acc[4][4] = {};
  const int r0 = tid >> 2, c0 = (tid & 3) * 8;
  const int r1 = r0 + 64;

  for (int k0 = 0; k0 < K; k0 += 32) {
    __syncthreads();
    uint4 a0 = *reinterpret_cast<const uint4*>(&A[(size_t)(m0 + r0) * K + k0 + c0]);
    uint4 a1 = *reinterpret_cast<const uint4*>(&A[(size_t)(m0 + r1) * K + k0 + c0]);
    uint4 b0 = *reinterpret_cast<const uint4*>(&Bw[(size_t)(n0 + r0) * K + k0 + c0]);
    uint4 b1 = *reinterpret_cast<const uint4*>(&Bw[(size_t)(n0 + r1) * K + k0 + c0]);
    *reinterpret_cast<uint4*>(&As[r0 * 40 + c0]) = a0;
    *reinterpret_cast<uint4*>(&As[r1 * 40 + c0]) = a1;
    *reinterpret_cast<uint4*>(&Bs[r0 * 40 + c0]) = b0;
    *reinterpret_cast<uint4*>(&Bs[r1 * 40 + c0]) = b1;
    __syncthreads();
    bf16x8 af[4], bf_[4];
#pragma unroll
    for (int mi = 0; mi < 4; ++mi)
      af[mi] = *reinterpret_cast<const bf16x8*>(&As[(wr * 64 + mi * 16 + l15) * 40 + l4 * 8]);
#pragma unroll
    for (int ni = 0; ni < 4; ++ni)
      bf_[ni] = *reinterpret_cast<const bf16x8*>(&Bs[(wc * 64 + ni * 16 + l15) * 40 + l4 * 8]);
#pragma unroll
    for (int mi = 0; mi < 4; ++mi)
#pragma unroll
      for (int ni = 0; ni < 4; ++ni)
        acc[mi][ni] = __builtin_amdgcn_mfma_f32_16x16x32_bf16(af[mi], bf_[ni], acc[mi][ni], 0, 0, 0);
  }

#pragma unroll
  for (int mi = 0; mi < 4; ++mi)
#pragma unroll
    for (int ni = 0; ni < 4; ++ni)
#pragma unroll
      for (int r = 0; r < 4; ++r) {
        const int row = m0 + wr * 64 + mi * 16 + l4 * 4 + r;
        const int col = n0 + wc * 64 + ni * 16 + l15;
        const float v = acc[mi][ni][r];
        if (EPI == 0) {
          const int which = col >> 10, hh = (col >> 6) & 15, d = col & 63;
          const int b = row >> 11, n = row & (Nn - 1);
          const size_t idx = (((size_t)b * Hn + hh) * Nn + n) * Dn + d;
          const bf16 val = __float2bfloat16(v);
          if (which == 0) q_raw[idx] = val;
          else if (which == 1) k_raw[idx] = val;
          else v_buf[idx] = val;
        } else {
          Cf[(size_t)row * N + col] = v;
        }
      }
}

// ---------------- RMSNorm + RoPE on q,k (in place), wave per row ----------------
__global__ __launch_bounds__(256) void norm_rope(bf16* __restrict__ q_raw,
                                                 bf16* __restrict__ k_raw,
                                                 const float* __restrict__ cosb,
                                                 const float* __restrict__ sinb,
                                                 const float* __restrict__ wq,
                                                 const float* __restrict__ wk) {
  const int row = blockIdx.x * 4 + (threadIdx.x >> 6);  // (b*H+h)*N + n
  const int lane = threadIdx.x & 63;
  const int n = row & (Nn - 1);
  const size_t base = (size_t)row * Dn + lane;
  const float c = cosb[n * Dn + lane], s = sinb[n * Dn + lane];
  float q = __bfloat162float(q_raw[base]);
  float k = __bfloat162float(k_raw[base]);
  float sq = q * q, sk = k * k;
#pragma unroll
  for (int off = 32; off >= 1; off >>= 1) {
    sq += __shfl_xor(sq, off);
    sk += __shfl_xor(sk, off);
  }
  const float rq = rsqrtf(sq * (1.f / Dn) + kEps) * wq[lane];
  const float rk = rsqrtf(sk * (1.f / Dn) + kEps) * wk[lane];
  const float qn = q * rq, kn = k * rk;
  const float qp = __shfl_xor(qn, 32), kp = __shfl_xor(kn, 32);
  const float sgn = (lane < 32) ? -1.f : 1.f;
  q_raw[base] = __float2bfloat16((qn * c + sgn * qp * s) * 0.125f);
  k_raw[base] = __float2bfloat16(kn * c + sgn * kp * s);
}

// ---------------- flash attention v3: swapped-operand, in-register softmax ----
// 4 waves x 32 q-rows (block = 128 q), KVBLK=64, double-buffered LDS, 1
// barrier/iter. S^T = mfma_32x32x16(K, Q) -> lane holds 32 scores for q =
// lane&31 (k-half selected by lane>>5). Softmax fully in-register; P->bf16 via
// v_cvt_pk_bf16_f32 + v_permlane32_swap_b32 feeds PV's B operand. PV computed
// as O^T = mfma(V^T, P^T) so O/m/l are lane-local per q-row.
__global__ __launch_bounds__(256, 4) void flash_attn(
    const bf16* __restrict__ Qb, const bf16* __restrict__ Kb,
    const bf16* __restrict__ Vb, bf16* __restrict__ Ob) {
  __shared__ __align__(16) char KsB[2][64 * 128];  // K[k][d], swz ((k&7)<<4)
  __shared__ __align__(16) char VtB[2][64 * 128];  // V^T[d][k], swz ((((d>>3)^d)&7)<<4)
  const int bh = blockIdx.y;
  const int q0 = blockIdx.x * 128;
  const int tid = threadIdx.x, lane = tid & 63, w = tid >> 6;
  const int l31 = lane & 31, hi = lane >> 5;
  const bf16* Qp = Qb + (size_t)bh * Nn * Dn;
  const bf16* Kp = Kb + (size_t)bh * Nn * Dn;
  const bf16* Vp = Vb + (size_t)bh * Nn * Dn;

  // Q fragments: lane holds Q[qrow][dm*16 + hi*8 + 0..7]
  const int qrow = q0 + w * 32 + l31;
  bf16x8 qf[4];
#pragma unroll
  for (int dm = 0; dm < 4; ++dm)
    qf[dm] = *reinterpret_cast<const bf16x8*>(&Qp[(size_t)qrow * Dn + dm * 16 + hi * 8]);

  f32x16 Ot0 = {}, Ot1 = {};  // O^T[dchunk][dlocal][q=l31]
  float m_r = -1e30f, l_r = 0.f;

  // staging: thread covers K/V rows {skk, skk+32}, d-cols sd0..sd0+7
  const int skk = tid >> 3, sd0 = (tid & 7) * 8;
  const int swzK = (skk & 7) << 4;
  const int koff0 = skk * 128 + ((sd0 * 2) ^ swzK);
  const int koff1 = (skk + 32) * 128 + ((sd0 * 2) ^ swzK);

  auto stage_v = [&](char* Vn, const uint4& a, const uint4& b) {
    const uint wa[4] = {a.x, a.y, a.z, a.w}, wb[4] = {b.x, b.y, b.z, b.w};
#pragma unroll
    for (int j = 0; j < 8; ++j) {
      const int d = sd0 + j;
      const int swz = (((d >> 3) ^ d) & 7) << 4;
      const unsigned short va = (j & 1) ? (unsigned short)(wa[j >> 1] >> 16)
                                        : (unsigned short)(wa[j >> 1] & 0xffff);
      const unsigned short vb2 = (j & 1) ? (unsigned short)(wb[j >> 1] >> 16)
                                         : (unsigned short)(wb[j >> 1] & 0xffff);
      *reinterpret_cast<unsigned short*>(Vn + d * 128 + ((skk * 2) ^ swz)) = va;
      *reinterpret_cast<unsigned short*>(Vn + d * 128 + ((skk * 2 + 64) ^ swz)) = vb2;
    }
  };

  // prologue: tile 0 -> buf0, tile 1 -> regs
  {
    uint4 cka = *reinterpret_cast<const uint4*>(&Kp[(size_t)skk * Dn + sd0]);
    uint4 ckb = *reinterpret_cast<const uint4*>(&Kp[(size_t)(skk + 32) * Dn + sd0]);
    uint4 cva = *reinterpret_cast<const uint4*>(&Vp[(size_t)skk * Dn + sd0]);
    uint4 cvb = *reinterpret_cast<const uint4*>(&Vp[(size_t)(skk + 32) * Dn + sd0]);
    *reinterpret_cast<uint4*>(KsB[0] + koff0) = cka;
    *reinterpret_cast<uint4*>(KsB[0] + koff1) = ckb;
    stage_v(VtB[0], cva, cvb);
  }
  uint4 nka = *reinterpret_cast<const uint4*>(&Kp[(size_t)(64 + skk) * Dn + sd0]);
  uint4 nkb = *reinterpret_cast<const uint4*>(&Kp[(size_t)(96 + skk) * Dn + sd0]);
  uint4 nva = *reinterpret_cast<const uint4*>(&Vp[(size_t)(64 + skk) * Dn + sd0]);
  uint4 nvb = *reinterpret_cast<const uint4*>(&Vp[(size_t)(96 + skk) * Dn + sd0]);
  __syncthreads();

  const int swzk_rd = (l31 & 7) << 4;
  int cur = 0;
  for (int k0 = 0; k0 < Nn; k0 += 64) {
    const char* Kc = KsB[cur];
    const char* Vc = VtB[cur];

    // ---- S^T = K · Q^T : 8 MFMAs ----
    f32x16 S0 = {}, S1 = {};
    __builtin_amdgcn_s_setprio(1);
#pragma unroll
    for (int dm = 0; dm < 4; ++dm) {
      bf16x8 kf = *reinterpret_cast<const bf16x8*>(
          Kc + l31 * 128 + ((dm * 32 + hi * 16) ^ swzk_rd));
      S0 = __builtin_amdgcn_mfma_f32_32x32x16_bf16(kf, qf[dm], S0, 0, 0, 0);
    }
#pragma unroll
    for (int dm = 0; dm < 4; ++dm) {
      bf16x8 kf = *reinterpret_cast<const bf16x8*>(
          Kc + (32 + l31) * 128 + ((dm * 32 + hi * 16) ^ swzk_rd));
      S1 = __builtin_amdgcn_mfma_f32_32x32x16_bf16(kf, qf[dm], S1, 0, 0, 0);
    }
    __builtin_amdgcn_s_setprio(0);

    // ---- online softmax, lane-local (q = l31; this lane owns 32 of 64 k) ----
    f32x16 tm;
#pragma unroll
    for (int i = 0; i < 16; ++i) tm[i] = fmaxf(S0[i], S1[i]);
#pragma unroll
    for (int i = 0; i < 8; ++i) tm[i] = fmaxf(tm[i], tm[i + 8]);
#pragma unroll
    for (int i = 0; i < 4; ++i) tm[i] = fmaxf(tm[i], tm[i + 4]);
    float mx = fmaxf(fmaxf(tm[0], tm[1]), fmaxf(tm[2], tm[3]));
    const float full = fmaxf(mx, __shfl_xor(mx, 32));
    if (__any(full > m_r + 8.f)) {  // defer-max (T13)
      const float mnew = fmaxf(m_r, full);
      const float al = __expf(m_r - mnew);
#pragma unroll
      for (int i = 0; i < 16; ++i) { Ot0[i] *= al; Ot1[i] *= al; }
      l_r *= al;
      m_r = mnew;
    }
    float ps = 0.f;
    uint wv[2][8];
#pragma unroll
    for (int kc = 0; kc < 2; ++kc) {
      float p[16];
#pragma unroll
      for (int i = 0; i < 16; ++i)
        p[i] = __expf((kc ? S1[i] : S0[i]) - m_r);
#pragma unroll
      for (int c = 0; c < 2; ++c) {
        ps += ((p[8 * c + 0] + p[8 * c + 1]) + (p[8 * c + 2] + p[8 * c + 3])) +
              ((p[8 * c + 4] + p[8 * c + 5]) + (p[8 * c + 6] + p[8 * c + 7]));
        uint w0, w1, w2, w3;
        asm("v_cvt_pk_bf16_f32 %0, %1, %2" : "=v"(w0) : "v"(p[8 * c + 0]), "v"(p[8 * c + 1]));
        asm("v_cvt_pk_bf16_f32 %0, %1, %2" : "=v"(w1) : "v"(p[8 * c + 2]), "v"(p[8 * c + 3]));
        asm("v_cvt_pk_bf16_f32 %0, %1, %2" : "=v"(w2) : "v"(p[8 * c + 4]), "v"(p[8 * c + 5]));
        asm("v_cvt_pk_bf16_f32 %0, %1, %2" : "=v"(w3) : "v"(p[8 * c + 6]), "v"(p[8 * c + 7]));
        asm("v_permlane32_swap_b32 %0, %1" : "+v"(w0), "+v"(w2));
        asm("v_permlane32_swap_b32 %0, %1" : "+v"(w1), "+v"(w3));
        wv[kc][c * 4 + 0] = w0; wv[kc][c * 4 + 1] = w1;
        wv[kc][c * 4 + 2] = w2; wv[kc][c * 4 + 3] = w3;
      }
    }
    ps += __shfl_xor(ps, 32);
    l_r += ps;

    // ---- O^T += V^T · P^T : 8 MFMAs ----
    __builtin_amdgcn_s_setprio(1);
#pragma unroll
    for (int s = 0; s < 4; ++s) {
      const uint4 uu = {wv[s >> 1][(s & 1) * 4 + 0], wv[s >> 1][(s & 1) * 4 + 1],
                        wv[s >> 1][(s & 1) * 4 + 2], wv[s >> 1][(s & 1) * 4 + 3]};
      const bf16x8 pa = __builtin_bit_cast(bf16x8, uu);
      {
        const int d = l31;
        const int swz = (((d >> 3) ^ d) & 7) << 4;
        bf16x8 vf = *reinterpret_cast<const bf16x8*>(Vc + d * 128 + ((s * 32 + hi * 16) ^ swz));
        Ot0 = __builtin_amdgcn_mfma_f32_32x32x16_bf16(vf, pa, Ot0, 0, 0, 0);
      }
      {
        const int d = 32 + l31;
        const int swz = (((d >> 3) ^ d) & 7) << 4;
        bf16x8 vf = *reinterpret_cast<const bf16x8*>(Vc + d * 128 + ((s * 32 + hi * 16) ^ swz));
        Ot1 = __builtin_amdgcn_mfma_f32_32x32x16_bf16(vf, pa, Ot1, 0, 0, 0);
      }
    }
    __builtin_amdgcn_s_setprio(0);

    // ---- write tile k0+64 (regs) -> buf[cur^1], issue loads for k0+128 ----
    if (k0 + 64 < Nn) {
      char* Kn = KsB[cur ^ 1];
      *reinterpret_cast<uint4*>(Kn + koff0) = nka;
      *reinterpret_cast<uint4*>(Kn + koff1) = nkb;
      stage_v(VtB[cur ^ 1], nva, nvb);
      if (k0 + 128 < Nn) {
        nka = *reinterpret_cast<const uint4*>(&Kp[(size_t)(k0 + 128 + skk) * Dn + sd0]);
        nkb = *reinterpret_cast<const uint4*>(&Kp[(size_t)(k0 + 160 + skk) * Dn + sd0]);
        nva = *reinterpret_cast<const uint4*>(&Vp[(size_t)(k0 + 128 + skk) * Dn + sd0]);
        nvb = *reinterpret_cast<const uint4*>(&Vp[(size_t)(k0 + 160 + skk) * Dn + sd0]);
      }
    }
    __syncthreads();
    cur ^= 1;
  }

  // ---- epilogue: O^T[d][q] / l -> attn[B][N][C] bf16, 8B stores ----
  const float inv = 1.f / l_r;
  const int b = bh >> 4, h = bh & 15;
#pragma unroll
  for (int dc = 0; dc < 2; ++dc)
#pragma unroll
    for (int a2 = 0; a2 < 4; ++a2) {
      const f32x16& O = dc ? Ot1 : Ot0;
      unsigned short u0 = __bfloat16_as_ushort(__float2bfloat16(O[a2 * 4 + 0] * inv));
      unsigned short u1 = __bfloat16_as_ushort(__float2bfloat16(O[a2 * 4 + 1] * inv));
      unsigned short u2 = __bfloat16_as_ushort(__float2bfloat16(O[a2 * 4 + 2] * inv));
      unsigned short u3 = __bfloat16_as_ushort(__float2bfloat16(O[a2 * 4 + 3] * inv));
      uint2 pk;
      pk.x = (uint)u0 | ((uint)u1 << 16);
      pk.y = (uint)u2 | ((uint)u3 << 16);
      const int col = h * 64 + dc * 32 + a2 * 8 + hi * 4;
      *reinterpret_cast<uint2*>(&Ob[((size_t)(b * Nn + qrow)) * Cn + col]) = pk;
    }
}

extern "C" void kernel_launch(void* const* d_in, const int* in_sizes, int n_in,
                              void* d_out, int out_size, void* d_ws, size_t ws_size,
                              hipStream_t stream) {
  const float* hs   = (const float*)d_in[0];
  const float* cosb = (const float*)d_in[1];
  const float* sinb = (const float*)d_in[2];
  const float* qkvw = (const float*)d_in[3];
  const float* outw = (const float*)d_in[4];
  const float* nqw  = (const float*)d_in[5];
  const float* nkw  = (const float*)d_in[6];
  float* out = (float*)d_out;

  char* ws = (char*)d_ws;
  size_t off = 0;
  bf16* hs_b   = (bf16*)(ws + off); off += (size_t)Bn * Nn * Cn * 2;
  bf16* qkvw_b = (bf16*)(ws + off); off += (size_t)3 * Cn * Cn * 2;
  bf16* outw_b = (bf16*)(ws + off); off += (size_t)Cn * Cn * 2;
  bf16* q_raw  = (bf16*)(ws + off); off += (size_t)Bn * Hn * Nn * Dn * 2;
  bf16* k_raw  = (bf16*)(ws + off); off += (size_t)Bn * Hn * Nn * Dn * 2;
  bf16* v_buf  = (bf16*)(ws + off); off += (size_t)Bn * Hn * Nn * Dn * 2;
  bf16* attn   = (bf16*)(ws + off); off += (size_t)Bn * Nn * Cn * 2;

  cvt_kernel<<<(Bn * Nn * Cn / 4 + 255) / 256, 256, 0, stream>>>(hs, hs_b, Bn * Nn * Cn / 4);
  cvt_kernel<<<(3 * Cn * Cn / 4 + 255) / 256, 256, 0, stream>>>(qkvw, qkvw_b, 3 * Cn * Cn / 4);
  cvt_kernel<<<(Cn * Cn / 4 + 255) / 256, 256, 0, stream>>>(outw, outw_b, Cn * Cn / 4);

  gemm_bt<0><<<dim3(3 * Cn / 128, Bn * Nn / 128), 256, 0, stream>>>(
      hs_b, qkvw_b, nullptr, q_raw, k_raw, v_buf, 3 * Cn, Cn);

  norm_rope<<<(Bn * Hn * Nn) / 4, 256, 0, stream>>>(q_raw, k_raw, cosb, sinb, nqw, nkw);

  flash_attn<<<dim3(Nn / 128, Bn * Hn), 256, 0, stream>>>(q_raw, k_raw, v_buf, attn);

  gemm_bt<1><<<dim3(Cn / 128, Bn * Nn / 128), 256, 0, stream>>>(
      attn, outw_b, out, nullptr, nullptr, nullptr, Cn, Cn);
}

// Round 4
// 265.774 us; speedup vs baseline: 1.4489x; 1.4489x over previous
//
#include <hip/hip_runtime.h>
#include <hip/hip_bf16.h>

typedef short bf16x8 __attribute__((ext_vector_type(8)));
typedef float f32x4 __attribute__((ext_vector_type(4)));
typedef float f32x16 __attribute__((ext_vector_type(16)));
typedef __hip_bfloat16 bf16;
typedef unsigned int uint;

static constexpr int Bn = 4, Nn = 2048, Cn = 1024, Hn = 16, Dn = 64;
static constexpr float kEps = 1e-6f;

// async global->LDS 16B per lane (linear dest: wave-uniform base + lane*16)
#define GLOAD_LDS16(gp, lp)                                                        \
  __builtin_amdgcn_global_load_lds(                                                \
      (const __attribute__((address_space(1))) unsigned int*)(gp),                 \
      (__attribute__((address_space(3))) unsigned int*)(lp), 16, 0, 0)

// ---------------- f32 -> bf16 convert (4 elems/thread) ----------------
__global__ __launch_bounds__(256) void cvt_kernel(const float* __restrict__ in,
                                                  bf16* __restrict__ out, int n4) {
  int i = blockIdx.x * 256 + threadIdx.x;
  if (i >= n4) return;
  const float4 v = reinterpret_cast<const float4*>(in)[i];
  bf16 t[4];
  t[0] = __float2bfloat16(v.x); t[1] = __float2bfloat16(v.y);
  t[2] = __float2bfloat16(v.z); t[3] = __float2bfloat16(v.w);
  reinterpret_cast<uint2*>(out)[i] = *reinterpret_cast<const uint2*>(t);
}

// ---------------- bf16 GEMM, C = A(MxK) * B(NxK)^T ----------------
template <int EPI>
__global__ __launch_bounds__(256) void gemm_bt(
    const bf16* __restrict__ A, const bf16* __restrict__ Bw,
    float* __restrict__ Cf, bf16* __restrict__ q_raw, bf16* __restrict__ k_raw,
    bf16* __restrict__ v_buf, int N, int K) {
  __shared__ bf16 As[128 * 40];
  __shared__ bf16 Bs[128 * 40];
  const int tid = threadIdx.x;
  const int lane = tid & 63, w = tid >> 6;
  const int wr = w >> 1, wc = w & 1;
  const int l15 = lane & 15, l4 = lane >> 4;
  const int m0 = blockIdx.y * 128, n0 = blockIdx.x * 128;
  f32x4 acc[4][4] = {};
  const int r0 = tid >> 2, c0 = (tid & 3) * 8;
  const int r1 = r0 + 64;

  for (int k0 = 0; k0 < K; k0 += 32) {
    __syncthreads();
    uint4 a0 = *reinterpret_cast<const uint4*>(&A[(size_t)(m0 + r0) * K + k0 + c0]);
    uint4 a1 = *reinterpret_cast<const uint4*>(&A[(size_t)(m0 + r1) * K + k0 + c0]);
    uint4 b0 = *reinterpret_cast<const uint4*>(&Bw[(size_t)(n0 + r0) * K + k0 + c0]);
    uint4 b1 = *reinterpret_cast<const uint4*>(&Bw[(size_t)(n0 + r1) * K + k0 + c0]);
    *reinterpret_cast<uint4*>(&As[r0 * 40 + c0]) = a0;
    *reinterpret_cast<uint4*>(&As[r1 * 40 + c0]) = a1;
    *reinterpret_cast<uint4*>(&Bs[r0 * 40 + c0]) = b0;
    *reinterpret_cast<uint4*>(&Bs[r1 * 40 + c0]) = b1;
    __syncthreads();
    bf16x8 af[4], bf_[4];
#pragma unroll
    for (int mi = 0; mi < 4; ++mi)
      af[mi] = *reinterpret_cast<const bf16x8*>(&As[(wr * 64 + mi * 16 + l15) * 40 + l4 * 8]);
#pragma unroll
    for (int ni = 0; ni < 4; ++ni)
      bf_[ni] = *reinterpret_cast<const bf16x8*>(&Bs[(wc * 64 + ni * 16 + l15) * 40 + l4 * 8]);
#pragma unroll
    for (int mi = 0; mi < 4; ++mi)
#pragma unroll
      for (int ni = 0; ni < 4; ++ni)
        acc[mi][ni] = __builtin_amdgcn_mfma_f32_16x16x32_bf16(af[mi], bf_[ni], acc[mi][ni], 0, 0, 0);
  }

#pragma unroll
  for (int mi = 0; mi < 4; ++mi)
#pragma unroll
    for (int ni = 0; ni < 4; ++ni)
#pragma unroll
      for (int r = 0; r < 4; ++r) {
        const int row = m0 + wr * 64 + mi * 16 + l4 * 4 + r;
        const int col = n0 + wc * 64 + ni * 16 + l15;
        const float v = acc[mi][ni][r];
        if (EPI == 0) {
          const int which = col >> 10, hh = (col >> 6) & 15, d = col & 63;
          const int b = row >> 11, n = row & (Nn - 1);
          const size_t idx = (((size_t)b * Hn + hh) * Nn + n) * Dn + d;
          const bf16 val = __float2bfloat16(v);
          if (which == 0) q_raw[idx] = val;
          else if (which == 1) k_raw[idx] = val;
          else v_buf[idx] = val;
        } else {
          Cf[(size_t)row * N + col] = v;
        }
      }
}

// ---------------- RMSNorm + RoPE on q,k (in place), wave per row ----------------
__global__ __launch_bounds__(256) void norm_rope(bf16* __restrict__ q_raw,
                                                 bf16* __restrict__ k_raw,
                                                 const float* __restrict__ cosb,
                                                 const float* __restrict__ sinb,
                                                 const float* __restrict__ wq,
                                                 const float* __restrict__ wk) {
  const int row = blockIdx.x * 4 + (threadIdx.x >> 6);  // (b*H+h)*N + n
  const int lane = threadIdx.x & 63;
  const int n = row & (Nn - 1);
  const size_t base = (size_t)row * Dn + lane;
  const float c = cosb[n * Dn + lane], s = sinb[n * Dn + lane];
  float q = __bfloat162float(q_raw[base]);
  float k = __bfloat162float(k_raw[base]);
  float sq = q * q, sk = k * k;
#pragma unroll
  for (int off = 32; off >= 1; off >>= 1) {
    sq += __shfl_xor(sq, off);
    sk += __shfl_xor(sk, off);
  }
  const float rq = rsqrtf(sq * (1.f / Dn) + kEps) * wq[lane];
  const float rk = rsqrtf(sk * (1.f / Dn) + kEps) * wk[lane];
  const float qn = q * rq, kn = k * rk;
  const float qp = __shfl_xor(qn, 32), kp = __shfl_xor(kn, 32);
  const float sgn = (lane < 32) ? -1.f : 1.f;
  q_raw[base] = __float2bfloat16((qn * c + sgn * qp * s) * 0.125f);
  k_raw[base] = __float2bfloat16(kn * c + sgn * kp * s);
}

// ---------------- flash attention v4 ----------------
// Same swapped-operand in-register-softmax structure as v3, with:
//  - launch_bounds(256,3): 170-VGPR budget -> no scratch spills (v3 spilled
//    ~0.5 GB/dispatch at the 128-reg cap; WRITE_SIZE 289 MB was the tell)
//  - K staged via global_load_lds (linear LDS dest tid*16, PRE-SWIZZLED global
//    source col ^ ((row&7)<<4); read side applies the same XOR)
//  - exp computed in place into S0/S1 (kills the p[16] temp)
__global__ __launch_bounds__(256, 3) void flash_attn(
    const bf16* __restrict__ Qb, const bf16* __restrict__ Kb,
    const bf16* __restrict__ Vb, bf16* __restrict__ Ob) {
  __shared__ __align__(16) char KsB[2][64 * 128];  // K[k][d], swz ((k&7)<<4)
  __shared__ __align__(16) char VtB[2][64 * 128];  // V^T[d][k], swz ((((d>>3)^d)&7)<<4)
  const int bh = blockIdx.y;
  const int q0 = blockIdx.x * 128;
  const int tid = threadIdx.x, lane = tid & 63, w = tid >> 6;
  const int l31 = lane & 31, hi = lane >> 5;
  const bf16* Qp = Qb + (size_t)bh * Nn * Dn;
  const bf16* Kp = Kb + (size_t)bh * Nn * Dn;
  const bf16* Vp = Vb + (size_t)bh * Nn * Dn;

  const int qrow = q0 + w * 32 + l31;
  bf16x8 qf[4];
#pragma unroll
  for (int dm = 0; dm < 4; ++dm)
    qf[dm] = *reinterpret_cast<const bf16x8*>(&Qp[(size_t)qrow * Dn + dm * 16 + hi * 8]);

  f32x16 Ot0 = {}, Ot1 = {};
  float m_r = -1e30f, l_r = 0.f;

  // staging mapping: thread covers K/V rows {skk, skk+32}, d-group sd0
  const int skk = tid >> 3, sd0 = (tid & 7) * 8;
  const int swzK = (skk & 7) << 4;
  const int srcKe = (((sd0 * 2) ^ swzK) >> 1);  // pre-swizzled source col (elems)

  auto stage_v = [&](char* Vn, const uint4& a, const uint4& b) {
    const uint wa[4] = {a.x, a.y, a.z, a.w}, wb[4] = {b.x, b.y, b.z, b.w};
#pragma unroll
    for (int j = 0; j < 8; ++j) {
      const int d = sd0 + j;
      const int swz = (((d >> 3) ^ d) & 7) << 4;
      const unsigned short va = (j & 1) ? (unsigned short)(wa[j >> 1] >> 16)
                                        : (unsigned short)(wa[j >> 1] & 0xffff);
      const unsigned short vb2 = (j & 1) ? (unsigned short)(wb[j >> 1] >> 16)
                                         : (unsigned short)(wb[j >> 1] & 0xffff);
      *reinterpret_cast<unsigned short*>(Vn + d * 128 + ((skk * 2) ^ swz)) = va;
      *reinterpret_cast<unsigned short*>(Vn + d * 128 + ((skk * 2 + 64) ^ swz)) = vb2;
    }
  };

  // prologue: tile0 K via async DMA, tile0 V via regs; preload tile1 V regs
  GLOAD_LDS16(Kp + (size_t)skk * Dn + srcKe, KsB[0] + tid * 16);
  GLOAD_LDS16(Kp + (size_t)(skk + 32) * Dn + srcKe, KsB[0] + tid * 16 + 4096);
  {
    uint4 cva = *reinterpret_cast<const uint4*>(&Vp[(size_t)skk * Dn + sd0]);
    uint4 cvb = *reinterpret_cast<const uint4*>(&Vp[(size_t)(skk + 32) * Dn + sd0]);
    stage_v(VtB[0], cva, cvb);
  }
  uint4 nva = *reinterpret_cast<const uint4*>(&Vp[(size_t)(64 + skk) * Dn + sd0]);
  uint4 nvb = *reinterpret_cast<const uint4*>(&Vp[(size_t)(96 + skk) * Dn + sd0]);
  __syncthreads();

  const int swzk_rd = (l31 & 7) << 4;
  int cur = 0;
  for (int k0 = 0; k0 < Nn; k0 += 64) {
    const char* Kc = KsB[cur];
    const char* Vc = VtB[cur];

    // ---- prefetch tile k0+64: K via DMA, V^T from regs; issue V loads k0+128
    if (k0 + 64 < Nn) {
      GLOAD_LDS16(Kp + (size_t)(k0 + 64 + skk) * Dn + srcKe, KsB[cur ^ 1] + tid * 16);
      GLOAD_LDS16(Kp + (size_t)(k0 + 96 + skk) * Dn + srcKe, KsB[cur ^ 1] + tid * 16 + 4096);
      stage_v(VtB[cur ^ 1], nva, nvb);
      if (k0 + 128 < Nn) {
        nva = *reinterpret_cast<const uint4*>(&Vp[(size_t)(k0 + 128 + skk) * Dn + sd0]);
        nvb = *reinterpret_cast<const uint4*>(&Vp[(size_t)(k0 + 160 + skk) * Dn + sd0]);
      }
    }

    // ---- S^T = K · Q^T : 8 MFMAs ----
    f32x16 S0 = {}, S1 = {};
    __builtin_amdgcn_s_setprio(1);
#pragma unroll
    for (int dm = 0; dm < 4; ++dm) {
      bf16x8 kf = *reinterpret_cast<const bf16x8*>(
          Kc + l31 * 128 + ((dm * 32 + hi * 16) ^ swzk_rd));
      S0 = __builtin_amdgcn_mfma_f32_32x32x16_bf16(kf, qf[dm], S0, 0, 0, 0);
    }
#pragma unroll
    for (int dm = 0; dm < 4; ++dm) {
      bf16x8 kf = *reinterpret_cast<const bf16x8*>(
          Kc + (32 + l31) * 128 + ((dm * 32 + hi * 16) ^ swzk_rd));
      S1 = __builtin_amdgcn_mfma_f32_32x32x16_bf16(kf, qf[dm], S1, 0, 0, 0);
    }
    __builtin_amdgcn_s_setprio(0);

    // ---- online softmax, lane-local (q = l31) ----
    f32x16 tm;
#pragma unroll
    for (int i = 0; i < 16; ++i) tm[i] = fmaxf(S0[i], S1[i]);
#pragma unroll
    for (int i = 0; i < 8; ++i) tm[i] = fmaxf(tm[i], tm[i + 8]);
#pragma unroll
    for (int i = 0; i < 4; ++i) tm[i] = fmaxf(tm[i], tm[i + 4]);
    float mx = fmaxf(fmaxf(tm[0], tm[1]), fmaxf(tm[2], tm[3]));
    const float full = fmaxf(mx, __shfl_xor(mx, 32));
    if (__any(full > m_r + 8.f)) {  // defer-max (T13)
      const float mnew = fmaxf(m_r, full);
      const float al = __expf(m_r - mnew);
#pragma unroll
      for (int i = 0; i < 16; ++i) { Ot0[i] *= al; Ot1[i] *= al; }
      l_r *= al;
      m_r = mnew;
    }
#pragma unroll
    for (int i = 0; i < 16; ++i) S0[i] = __expf(S0[i] - m_r);
#pragma unroll
    for (int i = 0; i < 16; ++i) S1[i] = __expf(S1[i] - m_r);
    float ps = 0.f;
    uint wv[2][8];
#pragma unroll
    for (int kc = 0; kc < 2; ++kc) {
      const f32x16& P = kc ? S1 : S0;
#pragma unroll
      for (int c = 0; c < 2; ++c) {
        ps += ((P[8 * c + 0] + P[8 * c + 1]) + (P[8 * c + 2] + P[8 * c + 3])) +
              ((P[8 * c + 4] + P[8 * c + 5]) + (P[8 * c + 6] + P[8 * c + 7]));
        uint w0, w1, w2, w3;
        asm("v_cvt_pk_bf16_f32 %0, %1, %2" : "=v"(w0) : "v"(P[8 * c + 0]), "v"(P[8 * c + 1]));
        asm("v_cvt_pk_bf16_f32 %0, %1, %2" : "=v"(w1) : "v"(P[8 * c + 2]), "v"(P[8 * c + 3]));
        asm("v_cvt_pk_bf16_f32 %0, %1, %2" : "=v"(w2) : "v"(P[8 * c + 4]), "v"(P[8 * c + 5]));
        asm("v_cvt_pk_bf16_f32 %0, %1, %2" : "=v"(w3) : "v"(P[8 * c + 6]), "v"(P[8 * c + 7]));
        asm("v_permlane32_swap_b32 %0, %1" : "+v"(w0), "+v"(w2));
        asm("v_permlane32_swap_b32 %0, %1" : "+v"(w1), "+v"(w3));
        wv[kc][c * 4 + 0] = w0; wv[kc][c * 4 + 1] = w1;
        wv[kc][c * 4 + 2] = w2; wv[kc][c * 4 + 3] = w3;
      }
    }
    ps += __shfl_xor(ps, 32);
    l_r += ps;

    // ---- O^T += V^T · P^T : 8 MFMAs ----
    __builtin_amdgcn_s_setprio(1);
#pragma unroll
    for (int s = 0; s < 4; ++s) {
      const uint4 uu = {wv[s >> 1][(s & 1) * 4 + 0], wv[s >> 1][(s & 1) * 4 + 1],
                        wv[s >> 1][(s & 1) * 4 + 2], wv[s >> 1][(s & 1) * 4 + 3]};
      const bf16x8 pa = __builtin_bit_cast(bf16x8, uu);
      {
        const int d = l31;
        const int swz = (((d >> 3) ^ d) & 7) << 4;
        bf16x8 vf = *reinterpret_cast<const bf16x8*>(Vc + d * 128 + ((s * 32 + hi * 16) ^ swz));
        Ot0 = __builtin_amdgcn_mfma_f32_32x32x16_bf16(vf, pa, Ot0, 0, 0, 0);
      }
      {
        const int d = 32 + l31;
        const int swz = (((d >> 3) ^ d) & 7) << 4;
        bf16x8 vf = *reinterpret_cast<const bf16x8*>(Vc + d * 128 + ((s * 32 + hi * 16) ^ swz));
        Ot1 = __builtin_amdgcn_mfma_f32_32x32x16_bf16(vf, pa, Ot1, 0, 0, 0);
      }
    }
    __builtin_amdgcn_s_setprio(0);

    __syncthreads();  // drains ds_writes + global_load_lds (vmcnt/lgkmcnt)
    cur ^= 1;
  }

  // ---- epilogue ----
  const float inv = 1.f / l_r;
  const int b = bh >> 4, h = bh & 15;
#pragma unroll
  for (int dc = 0; dc < 2; ++dc)
#pragma unroll
    for (int a2 = 0; a2 < 4; ++a2) {
      const f32x16& O = dc ? Ot1 : Ot0;
      unsigned short u0 = __bfloat16_as_ushort(__float2bfloat16(O[a2 * 4 + 0] * inv));
      unsigned short u1 = __bfloat16_as_ushort(__float2bfloat16(O[a2 * 4 + 1] * inv));
      unsigned short u2 = __bfloat16_as_ushort(__float2bfloat16(O[a2 * 4 + 2] * inv));
      unsigned short u3 = __bfloat16_as_ushort(__float2bfloat16(O[a2 * 4 + 3] * inv));
      uint2 pk;
      pk.x = (uint)u0 | ((uint)u1 << 16);
      pk.y = (uint)u2 | ((uint)u3 << 16);
      const int col = h * 64 + dc * 32 + a2 * 8 + hi * 4;
      *reinterpret_cast<uint2*>(&Ob[((size_t)(b * Nn + qrow)) * Cn + col]) = pk;
    }
}

extern "C" void kernel_launch(void* const* d_in, const int* in_sizes, int n_in,
                              void* d_out, int out_size, void* d_ws, size_t ws_size,
                              hipStream_t stream) {
  const float* hs   = (const float*)d_in[0];
  const float* cosb = (const float*)d_in[1];
  const float* sinb = (const float*)d_in[2];
  const float* qkvw = (const float*)d_in[3];
  const float* outw = (const float*)d_in[4];
  const float* nqw  = (const float*)d_in[5];
  const float* nkw  = (const float*)d_in[6];
  float* out = (float*)d_out;

  char* ws = (char*)d_ws;
  size_t off = 0;
  bf16* hs_b   = (bf16*)(ws + off); off += (size_t)Bn * Nn * Cn * 2;
  bf16* qkvw_b = (bf16*)(ws + off); off += (size_t)3 * Cn * Cn * 2;
  bf16* outw_b = (bf16*)(ws + off); off += (size_t)Cn * Cn * 2;
  bf16* q_raw  = (bf16*)(ws + off); off += (size_t)Bn * Hn * Nn * Dn * 2;
  bf16* k_raw  = (bf16*)(ws + off); off += (size_t)Bn * Hn * Nn * Dn * 2;
  bf16* v_buf  = (bf16*)(ws + off); off += (size_t)Bn * Hn * Nn * Dn * 2;
  bf16* attn   = (bf16*)(ws + off); off += (size_t)Bn * Nn * Cn * 2;

  cvt_kernel<<<(Bn * Nn * Cn / 4 + 255) / 256, 256, 0, stream>>>(hs, hs_b, Bn * Nn * Cn / 4);
  cvt_kernel<<<(3 * Cn * Cn / 4 + 255) / 256, 256, 0, stream>>>(qkvw, qkvw_b, 3 * Cn * Cn / 4);
  cvt_kernel<<<(Cn * Cn / 4 + 255) / 256, 256, 0, stream>>>(outw, outw_b, Cn * Cn / 4);

  gemm_bt<0><<<dim3(3 * Cn / 128, Bn * Nn / 128), 256, 0, stream>>>(
      hs_b, qkvw_b, nullptr, q_raw, k_raw, v_buf, 3 * Cn, Cn);

  norm_rope<<<(Bn * Hn * Nn) / 4, 256, 0, stream>>>(q_raw, k_raw, cosb, sinb, nqw, nkw);

  flash_attn<<<dim3(Nn / 128, Bn * Hn), 256, 0, stream>>>(q_raw, k_raw, v_buf, attn);

  gemm_bt<1><<<dim3(Cn / 128, Bn * Nn / 128), 256, 0, stream>>>(
      attn, outw_b, out, nullptr, nullptr, nullptr, Cn, Cn);
}